// Round 10
// baseline (1250.043 us; speedup 1.0000x reference)
//
#include <hip/hip_runtime.h>
#include <math.h>

typedef _Float16 f16;
typedef _Float16 h8  __attribute__((ext_vector_type(8)));
typedef _Float16 h4  __attribute__((ext_vector_type(4)));
typedef _Float16 h2  __attribute__((ext_vector_type(2)));
typedef float    f4  __attribute__((ext_vector_type(4)));

#define N_NODES 100000
#define VDIM    50000
#define N_EDGES 1600000
#define FDIM    128
#define CDIM    20
#define NEG_SLOPE 0.01f

#define NPART 782                    // partitions of 128 dst nodes
#define PCAP  2560                   // static region per partition (mean 2046, +11 sigma)
#define RTOT  (NPART * PCAP)         // total record slots
#define NB    1000                   // histogram/scatter blocks (~3.9/CU)
#define EPB   (N_EDGES / NB)         // 1600 edges per block (exact)
#define PBUF  2944                   // repack LDS capacity
#define GP    136                    // LDS pitch in halves
#define NSL   8                      // feature slices (1 per XCD)
#define SF    16                     // features per slice

// ---------------------------------------------------------------------------
// K1: [0,NB) per-block dst-partition histograms (LDS atomics, proven);
// then 128 blocks transpose W0/W1 to fp16 [n][k]; last 16 blocks build W2T.
// ---------------------------------------------------------------------------
__global__ __launch_bounds__(256) void k1_build(const int* __restrict__ dst,
                                                int* __restrict__ histG,
                                                const float* __restrict__ W0,
                                                const float* __restrict__ W1,
                                                const float* __restrict__ W2,
                                                f16* __restrict__ W0T,
                                                f16* __restrict__ W1T,
                                                f16* __restrict__ W2T) {
    int b = blockIdx.x, t = threadIdx.x;
    if (b < NB) {
        __shared__ unsigned lh[NPART];
        for (int i = t; i < NPART; i += 256) lh[i] = 0;
        __syncthreads();
        int e0 = b * EPB;
        for (int i = t; i < EPB; i += 256)
            atomicAdd(&lh[dst[e0 + i] >> 7], 1u);
        __syncthreads();
        for (int i = t; i < NPART; i += 256) histG[b * NPART + i] = (int)lh[i];
    } else if (b < NB + 128) {
        int o = (b - NB) * 256 + t;                   // 32768 total
        const float* W = (o < 16384) ? W0 : W1;
        f16* T = (o < 16384) ? W0T : W1T;
        int o2 = o & 16383;
        int n = o2 >> 7, k = o2 & 127;
        T[o2] = (f16)W[k * 128 + n];
    } else {
        int o = (b - NB - 128) * 256 + t;             // 4096 total
        int cc = o >> 7, k = o & 127;
        W2T[o] = (cc < CDIM) ? (f16)W2[k * CDIM + cc] : (f16)0.f;
    }
}

// ---------------------------------------------------------------------------
// KH0: h0 = fp16(emb @ W0), 50K x 128, written COLUMN-BLOCKED:
// h0CB[slice][row][16] so layer-0 slice gathers are 32B contiguous.
// ---------------------------------------------------------------------------
__global__ __launch_bounds__(256, 8) void kh0(const float* __restrict__ emb,
                                              const f16* __restrict__ W0T,
                                              f16* __restrict__ h0CB) {
    __shared__ f16 Xs[32 * GP];
    int t = threadIdx.x;
    int r0 = blockIdx.x * 32;
    for (int i = t; i < 32 * 32; i += 256) {          // 32 rows x 32 float4
        int row = i >> 5, q = i & 31;
        int v = r0 + row;
        float4 vv = (v < VDIM) ? ((const float4*)emb)[(size_t)v * 32 + q]
                               : make_float4(0.f, 0.f, 0.f, 0.f);
        h4 o; o[0] = (f16)vv.x; o[1] = (f16)vv.y; o[2] = (f16)vv.z; o[3] = (f16)vv.w;
        *(h4*)(Xs + row * GP + q * 4) = o;
    }
    __syncthreads();
    int wave = t >> 6, lane = t & 63;
    int quad = lane >> 4, l15 = lane & 15;
    int mtile = wave & 1, nh = wave >> 1;
    f4 a4[4]; f4 zero = {0.f, 0.f, 0.f, 0.f};
    #pragma unroll
    for (int i = 0; i < 4; ++i) a4[i] = zero;
    #pragma unroll
    for (int kk = 0; kk < 128; kk += 32) {
        h8 a = *(h8*)(Xs + (mtile * 16 + l15) * GP + kk + quad * 8);
        #pragma unroll
        for (int nt4 = 0; nt4 < 4; ++nt4) {
            int nt = nh * 4 + nt4;
            h8 b = *(const h8*)(W0T + (nt * 16 + l15) * 128 + kk + quad * 8);
            a4[nt4] = __builtin_amdgcn_mfma_f32_16x16x32_f16(a, b, a4[nt4], 0, 0, 0);
        }
    }
    #pragma unroll
    for (int nt4 = 0; nt4 < 4; ++nt4) {
        int col = (nh * 4 + nt4) * 16 + l15;
        int sl = col >> 4, cw = col & 15;
        #pragma unroll
        for (int r = 0; r < 4; ++r) {
            int row = r0 + mtile * 16 + quad * 4 + r;
            if (row < VDIM)
                h0CB[(size_t)sl * VDIM * SF + (size_t)row * SF + cw] = (f16)a4[nt4][r];
        }
    }
}

// ---------------------------------------------------------------------------
// K2: one wave per partition; scan NB per-block counts (16/lane) -> offsets.
// ---------------------------------------------------------------------------
__global__ __launch_bounds__(256) void k2_seed(int* __restrict__ histG,
                                               int* __restrict__ ptot) {
    int w = blockIdx.x * 4 + (threadIdx.x >> 6);
    if (w >= NPART) return;
    int lane = threadIdx.x & 63;
    int base = w * PCAP;
    int v[16], pre[16], s = 0;
    #pragma unroll
    for (int i = 0; i < 16; ++i) {
        int idx = lane * 16 + i;
        v[i] = (idx < NB) ? histG[idx * NPART + w] : 0;
    }
    #pragma unroll
    for (int i = 0; i < 16; ++i) { pre[i] = s; s += v[i]; }
    int ss = s;
    #pragma unroll
    for (int off = 1; off < 64; off <<= 1) {
        int u = __shfl_up(ss, off);
        if (lane >= off) ss += u;
    }
    if (lane == 63) ptot[w] = ss;                     // partition total
    int wexcl = ss - s;
    #pragma unroll
    for (int i = 0; i < 16; ++i) {
        int idx = lane * 16 + i;
        if (idx < NB) histG[idx * NPART + w] = base + wexcl + pre[i];
    }
}

// ---------------------------------------------------------------------------
// K3: deterministic scatter via LDS cursors seeded from exact offsets.
// ---------------------------------------------------------------------------
__global__ __launch_bounds__(256) void k3_scatter(const int* __restrict__ src,
                                                  const int* __restrict__ dst,
                                                  const float* __restrict__ ew,
                                                  const int* __restrict__ histG,
                                                  uint2* __restrict__ recs) {
    __shared__ unsigned cur[NPART];
    int b = blockIdx.x, t = threadIdx.x;
    for (int i = t; i < NPART; i += 256) cur[i] = (unsigned)histG[b * NPART + i];
    __syncthreads();
    int e0 = b * EPB;
    for (int i = t; i < EPB; i += 256) {
        int e = e0 + i;
        int s = src[e], d = dst[e];
        int p = d >> 7, dl = d & 127;
        unsigned pos = atomicAdd(&cur[p], 1u);        // LDS atomic only
        if (pos < (unsigned)((p + 1) * PCAP)) {       // ~1e-20 overflow guard
            uint2 r; r.x = ((unsigned)dl << 17) | (unsigned)s; r.y = __float_as_uint(ew[e]);
            recs[pos] = r;
        }
    }
}

// ---------------------------------------------------------------------------
// K4: per-partition repack: sort records by dst_local in LDS, emit
// nstart/ncnt, weighted degree -> dinv, strips dl, emits vrec16 = ids[src].
// ---------------------------------------------------------------------------
__global__ __launch_bounds__(256) void k4_repack(uint2* __restrict__ recs,
                                                 const int* __restrict__ ptot,
                                                 const int* __restrict__ ids,
                                                 int* __restrict__ nstart,
                                                 int* __restrict__ ncnt,
                                                 float* __restrict__ dinv,
                                                 unsigned short* __restrict__ vrec16) {
    __shared__ uint2    buf[PBUF];                    // 23.5 KB
    __shared__ float    wsum[128];
    __shared__ unsigned hcnt[128], pref[128], cur[128];
    int p = blockIdx.x, t = threadIdx.x;
    if (t < 128) { hcnt[t] = 0; wsum[t] = 0.f; }
    __syncthreads();
    int base = p * PCAP;
    int c = ptot[p];
    if (c > PCAP) c = PCAP;
    for (int i = t; i < c; i += 256) {
        uint2 r = recs[base + i];
        buf[i] = r;
        int dl = r.x >> 17;
        atomicAdd(&hcnt[dl], 1u);
        atomicAdd(&wsum[dl], __uint_as_float(r.y));
    }
    __syncthreads();
    if (t == 0) {
        unsigned s = 0;
        for (int k = 0; k < 128; ++k) { pref[k] = s; s += hcnt[k]; }
    }
    __syncthreads();
    if (t < 128) {
        cur[t] = pref[t];
        int g = p * 128 + t;
        if (g < N_NODES) {
            nstart[g] = base + (int)pref[t];
            ncnt[g]   = (int)hcnt[t];
            dinv[g]   = rsqrtf(wsum[t] + 1.0f);
        }
    }
    __syncthreads();
    for (int i = t; i < c; i += 256) {
        uint2 r = buf[i];
        int dl = r.x >> 17;
        unsigned pos = atomicAdd(&cur[dl], 1u);
        int s = (int)(r.x & 0x1FFFFu);
        uint2 o; o.x = (unsigned)s; o.y = r.y;
        recs[base + pos]   = o;
        vrec16[base + pos] = (unsigned short)ids[s];
    }
}

// ---------------------------------------------------------------------------
// aggL0 (R23): slice-parallel layer-0 aggregation over h0CB.
// slice = blockIdx.x & 7 -> XCD round-robin pins each 1.6MB h0 slice into
// one XCD's L2. 8 lanes per node (lane owns 2 of 16 slice-features), zero
// cross-lane reduction. recs/vrec16 read NONTEMPORALLY (streamed 8x; must
// not evict the resident x-slice). x1 = leaky(dn*agg + dn^2*self + b0),
// written column-blocked for aggL1's gathers.
// ---------------------------------------------------------------------------
__global__ __launch_bounds__(256, 8) void aggL0(const f16* __restrict__ h0CB,
                                                const int* __restrict__ ids,
                                                const float* __restrict__ dinv,
                                                const int* __restrict__ nstart,
                                                const int* __restrict__ ncnt,
                                                const uint2* __restrict__ recs,
                                                const unsigned short* __restrict__ vrec16,
                                                const float* __restrict__ b0,
                                                f16* __restrict__ x1CB) {
    int t = threadIdx.x;
    int slice = blockIdx.x & 7;
    int nblk  = blockIdx.x >> 3;
    int wave = t >> 6, lane = t & 63;
    int ng = lane >> 3, fp = lane & 7;
    int node = nblk * 32 + wave * 8 + ng;
    int st = nstart[node], c = ncnt[node];

    int cc = c < 64 ? c : 64;
    int mc = cc;
    #pragma unroll
    for (int off = 8; off < 64; off <<= 1) {
        int u = __shfl_xor(mc, off);
        mc = u > mc ? u : mc;
    }
    const f16* xs = h0CB + (size_t)slice * VDIM * SF + fp * 2;
    float a0 = 0.f, a1 = 0.f;
    #pragma unroll 4
    for (int j = 0; j < mc; ++j) {
        int idx = st + (j < c ? j : (c > 0 ? c - 1 : 0));
        if (idx >= RTOT) idx = RTOT - 1;
        unsigned long long rv =
            __builtin_nontemporal_load((const unsigned long long*)(recs + idx));
        int s = (int)(rv & 0x1FFFFu);
        float ew = __uint_as_float((unsigned)(rv >> 32));
        unsigned v = __builtin_nontemporal_load(vrec16 + idx);
        if (v >= VDIM) v = 0;                         // garbage-slot clamp
        float cf = (j < c) ? dinv[s] * ew : 0.f;
        h2 xv = *(const h2*)(xs + (size_t)v * SF);
        a0 += cf * (float)xv[0];
        a1 += cf * (float)xv[1];
    }
    for (int j = 64; j < c; ++j) {                    // rare tail (deg > 64)
        uint2 r = recs[st + j];
        int s = (int)(r.x & 0x1FFFFu);
        int v = ids[s];
        float cf = dinv[s] * __uint_as_float(r.y);
        h2 xv = *(const h2*)(xs + (size_t)v * SF);
        a0 += cf * (float)xv[0];
        a1 += cf * (float)xv[1];
    }
    float dn = dinv[node], d2 = dn * dn;
    int vn = ids[node];
    h2 sv = *(const h2*)(xs + (size_t)vn * SF);
    float v0 = dn * a0 + d2 * (float)sv[0] + b0[slice * SF + fp * 2];
    float v1 = dn * a1 + d2 * (float)sv[1] + b0[slice * SF + fp * 2 + 1];
    v0 = v0 > 0.f ? v0 : NEG_SLOPE * v0;
    v1 = v1 > 0.f ? v1 : NEG_SLOPE * v1;
    h2 o; o[0] = (f16)v0; o[1] = (f16)v1;
    *(h2*)(x1CB + (size_t)slice * N_NODES * SF + (size_t)node * SF + fp * 2) = o;
}

// ---------------------------------------------------------------------------
// aggL1 (R23): slice-parallel z1 = A.x1 over x1CB (3.2MB/slice, L2-fits).
// Output z1 row-major (nontemporal store) for gemmL1's streaming read.
// ---------------------------------------------------------------------------
__global__ __launch_bounds__(256, 8) void aggL1(const f16* __restrict__ x1CB,
                                                const float* __restrict__ dinv,
                                                const int* __restrict__ nstart,
                                                const int* __restrict__ ncnt,
                                                const uint2* __restrict__ recs,
                                                f16* __restrict__ z1) {
    int t = threadIdx.x;
    int slice = blockIdx.x & 7;
    int nblk  = blockIdx.x >> 3;
    int wave = t >> 6, lane = t & 63;
    int ng = lane >> 3, fp = lane & 7;
    int node = nblk * 32 + wave * 8 + ng;
    int st = nstart[node], c = ncnt[node];

    int cc = c < 64 ? c : 64;
    int mc = cc;
    #pragma unroll
    for (int off = 8; off < 64; off <<= 1) {
        int u = __shfl_xor(mc, off);
        mc = u > mc ? u : mc;
    }
    const f16* xs = x1CB + (size_t)slice * N_NODES * SF + fp * 2;
    float a0 = 0.f, a1 = 0.f;
    #pragma unroll 4
    for (int j = 0; j < mc; ++j) {
        int idx = st + (j < c ? j : (c > 0 ? c - 1 : 0));
        if (idx >= RTOT) idx = RTOT - 1;
        unsigned long long rv =
            __builtin_nontemporal_load((const unsigned long long*)(recs + idx));
        int s = (int)(rv & 0x1FFFFu);
        if (s >= N_NODES) s = 0;                      // garbage-slot clamp
        float ew = __uint_as_float((unsigned)(rv >> 32));
        float cf = (j < c) ? dinv[s] * ew : 0.f;
        h2 xv = *(const h2*)(xs + (size_t)s * SF);
        a0 += cf * (float)xv[0];
        a1 += cf * (float)xv[1];
    }
    for (int j = 64; j < c; ++j) {                    // rare tail (deg > 64)
        uint2 r = recs[st + j];
        int s = (int)(r.x & 0x1FFFFu);
        float cf = dinv[s] * __uint_as_float(r.y);
        h2 xv = *(const h2*)(xs + (size_t)s * SF);
        a0 += cf * (float)xv[0];
        a1 += cf * (float)xv[1];
    }
    float dn = dinv[node], d2 = dn * dn;
    h2 sv = *(const h2*)(xs + (size_t)node * SF);
    h2 o;
    o[0] = (f16)(dn * a0 + d2 * (float)sv[0]);
    o[1] = (f16)(dn * a1 + d2 * (float)sv[1]);
    __builtin_nontemporal_store(*(unsigned*)&o,
        (unsigned*)(z1 + (size_t)node * 128 + slice * SF + fp * 2));
}

// ---------------------------------------------------------------------------
// gemmL1 (R23): x2 = leaky(z1 @ W1 + b1) in LDS; y = x2 @ W2 -> ybuf.
// (fusedL1's proven GEMM body; agg replaced by a streaming z1 tile load.)
// ---------------------------------------------------------------------------
__global__ __launch_bounds__(256, 8) void gemmL1(const f16* __restrict__ z1,
                                                 const f16* __restrict__ WT,
                                                 const float* __restrict__ bias,
                                                 const f16* __restrict__ W2T,
                                                 f16* __restrict__ Y) {
    __shared__ f16 Xs[32 * GP];
    int t = threadIdx.x;
    const f16* zb = z1 + (size_t)blockIdx.x * 32 * 128;
    #pragma unroll
    for (int k = t; k < 512; k += 256) {              // 32 rows x 16 h8-chunks? 512 = 32*16
        int row = k >> 4, off = (k & 15) * 8;
        *(h8*)(Xs + row * GP + off) = *(const h8*)(zb + row * 128 + off);
    }
    __syncthreads();

    int wave = t >> 6, lane = t & 63;
    int quad = lane >> 4, l15 = lane & 15;
    int mtile = wave & 1, nh = wave >> 1;
    f4 a4[4]; f4 zero = {0.f, 0.f, 0.f, 0.f};
    #pragma unroll
    for (int i = 0; i < 4; ++i) a4[i] = zero;
    #pragma unroll
    for (int kk = 0; kk < 128; kk += 32) {
        h8 a = *(h8*)(Xs + (mtile * 16 + l15) * GP + kk + quad * 8);
        #pragma unroll
        for (int nt4 = 0; nt4 < 4; ++nt4) {
            int nt = nh * 4 + nt4;
            h8 b = *(const h8*)(WT + (nt * 16 + l15) * 128 + kk + quad * 8);
            a4[nt4] = __builtin_amdgcn_mfma_f32_16x16x32_f16(a, b, a4[nt4], 0, 0, 0);
        }
    }
    __syncthreads();                                  // z reads done
    #pragma unroll
    for (int nt4 = 0; nt4 < 4; ++nt4) {               // x2 = leaky(acc+b) -> LDS
        int col = (nh * 4 + nt4) * 16 + l15;
        float bb = bias[col];
        #pragma unroll
        for (int r = 0; r < 4; ++r) {
            float v = a4[nt4][r] + bb;
            v = v > 0.f ? v : NEG_SLOPE * v;
            Xs[(mtile * 16 + quad * 4 + r) * GP + col] = (f16)v;
        }
    }
    __syncthreads();
    int mt2 = wave & 1, nt2 = wave >> 1;              // 32x32 y tile, 4 waves
    f4 ya = zero;
    #pragma unroll
    for (int kk = 0; kk < 128; kk += 32) {
        h8 a = *(h8*)(Xs + (mt2 * 16 + l15) * GP + kk + quad * 8);
        h8 b = *(const h8*)(W2T + (nt2 * 16 + l15) * GP - GP + 0);  // placeholder (fixed below)
        (void)b;
        h8 b2v = *(const h8*)(W2T + (nt2 * 16 + l15) * 128 + kk + quad * 8);
        ya = __builtin_amdgcn_mfma_f32_16x16x32_f16(a, b2v, ya, 0, 0, 0);
    }
    size_t rbase = (size_t)blockIdx.x * 32;
    #pragma unroll
    for (int r = 0; r < 4; ++r) {
        size_t row = rbase + mt2 * 16 + quad * 4 + r;
        Y[row * 32 + nt2 * 16 + l15] = (f16)ya[r];
    }
}

// ---------------------------------------------------------------------------
// agg20L: out = LSM( b2 + dn*sum(dinv[s]*ew*Y[s]) + dn^2*Y[n] ). (R22)
// ---------------------------------------------------------------------------
__global__ __launch_bounds__(256) void agg20L(const f16* __restrict__ Y,
                                              const float* __restrict__ dinv,
                                              const int* __restrict__ nstart,
                                              const int* __restrict__ ncnt,
                                              const uint2* __restrict__ recs,
                                              const float* __restrict__ b2,
                                              float* __restrict__ out) {
    int wave = threadIdx.x >> 6, lane = threadIdx.x & 63;
    int g = lane >> 3, l7 = lane & 7;
    int node = blockIdx.x * 4 + wave;
    int st = nstart[node], c = ncnt[node];

    int ci = lane < c ? lane : (c > 0 ? c - 1 : 0);
    int addr = st + ci;
    if (addr >= RTOT) addr = RTOT - 1;
    uint2 r0 = recs[addr];
    int   sidx0 = (int)(r0.x & 0x1FFFFu);
    float cf0 = (lane < c) ? dinv[sidx0] * __uint_as_float(r0.y) : 0.f;

    float acc[4];
    #pragma unroll
    for (int k = 0; k < 4; ++k) acc[k] = 0.f;

    int cl = c < 64 ? c : 64;
    #pragma unroll 4
    for (int j = 0; j < cl; j += 8) {
        int jj = j + g;
        float cc = __shfl(cf0, jj);
        int   si = __shfl(sidx0, jj);
        h4 hh = *(const h4*)(Y + (size_t)si * 32 + l7 * 4);
        #pragma unroll
        for (int k = 0; k < 4; ++k) acc[k] += cc * (float)hh[k];
    }
    for (int j = 64; j < c; j += 8) {                 // rare spill-over
        int jj = j + g;
        int idx = st + (jj < c ? jj : c - 1);
        uint2 r = recs[idx];
        int s = (int)(r.x & 0x1FFFFu);
        float cf = dinv[s] * __uint_as_float(r.y);
        float cc = (jj < c) ? cf : 0.f;
        h4 hh = *(const h4*)(Y + (size_t)s * 32 + l7 * 4);
        #pragma unroll
        for (int k = 0; k < 4; ++k) acc[k] += cc * (float)hh[k];
    }
    #pragma unroll
    for (int k = 0; k < 4; ++k) {
        acc[k] += __shfl_xor(acc[k], 8);
        acc[k] += __shfl_xor(acc[k], 16);
        acc[k] += __shfl_xor(acc[k], 32);
    }
    float dn = dinv[node], d2 = dn * dn;
    h4 hz = *(const h4*)(Y + (size_t)node * 32 + l7 * 4);
    bool live = (l7 < 5);                             // 5 lanes x 4 = 20 classes
    float tv[4];
    float mx = -INFINITY;
    #pragma unroll
    for (int k = 0; k < 4; ++k) {
        tv[k] = live ? (b2[l7 * 4 + k] + dn * acc[k] + d2 * (float)hz[k]) : -INFINITY;
        mx = fmaxf(mx, tv[k]);
    }
    #pragma unroll
    for (int off = 1; off <= 4; off <<= 1) mx = fmaxf(mx, __shfl_xor(mx, off));
    float ex = 0.f;
    if (live) {
        #pragma unroll
        for (int k = 0; k < 4; ++k) ex += expf(tv[k] - mx);
    }
    #pragma unroll
    for (int off = 1; off <= 4; off <<= 1) ex += __shfl_xor(ex, off);
    float ls = logf(ex);
    if (g == 0 && live) {
        float4 o;
        o.x = tv[0] - mx - ls; o.y = tv[1] - mx - ls;
        o.z = tv[2] - mx - ls; o.w = tv[3] - mx - ls;
        *(float4*)(out + (size_t)node * CDIM + l7 * 4) = o;
    }
}

// ---------------------------------------------------------------------------
extern "C" void kernel_launch(void* const* d_in, const int* in_sizes, int n_in,
                              void* d_out, int out_size, void* d_ws, size_t ws_size,
                              hipStream_t stream) {
    (void)in_sizes; (void)n_in; (void)out_size; (void)ws_size;
    const int*   node_ids = (const int*)d_in[0];
    const int*   e_src    = (const int*)d_in[1];
    const int*   e_dst    = e_src + N_EDGES;
    const float* edge_w   = (const float*)d_in[2];
    const float* emb      = (const float*)d_in[3];
    const float* W0       = (const float*)d_in[4];
    const float* b0       = (const float*)d_in[5];
    const float* W1       = (const float*)d_in[6];
    const float* b1       = (const float*)d_in[7];
    const float* W2       = (const float*)d_in[8];
    const float* b2       = (const float*)d_in[9];
    float* out = (float*)d_out;

    char* w = (char*)d_ws;
    size_t off = 0;
    auto alloc = [&](size_t bytes) {
        void* p = w + off;
        off = (off + bytes + 255) & ~(size_t)255;
        return p;
    };
    f16*   h0CB   = (f16*)alloc((size_t)VDIM * FDIM * 2);        // 12.8 MB
    f16*   x1CB   = (f16*)alloc((size_t)N_NODES * FDIM * 2);     // 25.6 MB
    f16*   z1     = (f16*)alloc((size_t)N_NODES * FDIM * 2);     // 25.6 MB
    f16*   ybuf   = (f16*)alloc((size_t)N_NODES * 32 * 2);       // 6.4 MB
    int*   histG  = (int*)alloc((size_t)NB * NPART * 4);         // 3.1 MB
    int*   ptot   = (int*)alloc((size_t)NPART * 4);
    int*   nstart = (int*)alloc((size_t)N_NODES * 4);
    int*   ncnt   = (int*)alloc((size_t)N_NODES * 4);
    float* dinv   = (float*)alloc((size_t)N_NODES * 4 + 131072 * 4);  // +OOB pad
    f16*   W0T    = (f16*)alloc(16384 * 2);
    f16*   W1T    = (f16*)alloc(16384 * 2);
    f16*   W2T    = (f16*)alloc(32 * 128 * 2);
    uint2* recs   = (uint2*)alloc((size_t)NPART * PCAP * 8);     // 16.0 MB
    unsigned short* vrec16 = (unsigned short*)alloc((size_t)NPART * PCAP * 2); // 4 MB

    k1_build<<<NB + 128 + 16, 256, 0, stream>>>(
        e_dst, histG, W0, W1, W2, W0T, W1T, W2T);
    k2_seed<<<(NPART + 3) / 4, 256, 0, stream>>>(histG, ptot);
    kh0<<<(VDIM + 31) / 32, 256, 0, stream>>>(emb, W0T, h0CB);   // h0 = emb @ W0 (CB)
    k3_scatter<<<NB, 256, 0, stream>>>(e_src, e_dst, edge_w, histG, recs);
    k4_repack<<<NPART, 256, 0, stream>>>(recs, ptot, node_ids, nstart, ncnt, dinv, vrec16);

    int sblocks = NSL * (N_NODES / 32);              // 25000: slice = bid & 7 -> XCD
    // layer 0:  x1 = leaky(A.(emb@W0) + b0)  (slice-parallel, L2-resident tables)
    aggL0<<<sblocks, 256, 0, stream>>>(h0CB, node_ids, dinv, nstart, ncnt,
                                       recs, vrec16, b0, x1CB);
    // layer 1 agg: z1 = A.x1   (slice-parallel)
    aggL1<<<sblocks, 256, 0, stream>>>(x1CB, dinv, nstart, ncnt, recs, z1);
    // layer 1 GEMM + 128->20:  y = leaky(z1 W1 + b1) W2
    gemmL1<<<N_NODES / 32, 256, 0, stream>>>(z1, W1T, b1, W2T, ybuf);
    // out = LSM(b2 + A.y)
    agg20L<<<N_NODES / 4, 256, 0, stream>>>(ybuf, dinv, nstart, ncnt, recs, b2, out);
}

// Round 11
// 400.114 us; speedup vs baseline: 3.1242x; 3.1242x over previous
//
#include <hip/hip_runtime.h>
#include <math.h>

typedef _Float16 f16;
typedef _Float16 h8  __attribute__((ext_vector_type(8)));
typedef _Float16 h4  __attribute__((ext_vector_type(4)));
typedef _Float16 h2  __attribute__((ext_vector_type(2)));
typedef float    f4  __attribute__((ext_vector_type(4)));

#define N_NODES 100000
#define VDIM    50000
#define N_EDGES 1600000
#define FDIM    128
#define CDIM    20
#define NEG_SLOPE 0.01f

#define NPART 782                    // partitions of 128 dst nodes
#define PCAP  2560                   // static region per partition (mean 2046, +11 sigma)
#define RTOT  (NPART * PCAP)         // total record slots
#define NB    1000                   // histogram/scatter blocks (~3.9/CU)
#define EPB   (N_EDGES / NB)         // 1600 edges per block (exact)
#define PBUF  2944                   // repack LDS capacity
#define GP    136                    // LDS pitch in halves

// ---------------------------------------------------------------------------
// K1: [0,NB) per-block dst-partition histograms (LDS atomics, proven);
// then 128 blocks transpose W0/W1 to fp16 [n][k]; last 16 blocks build W2T.
// ---------------------------------------------------------------------------
__global__ __launch_bounds__(256) void k1_build(const int* __restrict__ dst,
                                                int* __restrict__ histG,
                                                const float* __restrict__ W0,
                                                const float* __restrict__ W1,
                                                const float* __restrict__ W2,
                                                f16* __restrict__ W0T,
                                                f16* __restrict__ W1T,
                                                f16* __restrict__ W2T) {
    int b = blockIdx.x, t = threadIdx.x;
    if (b < NB) {
        __shared__ unsigned lh[NPART];
        for (int i = t; i < NPART; i += 256) lh[i] = 0;
        __syncthreads();
        int e0 = b * EPB;
        for (int i = t; i < EPB; i += 256)
            atomicAdd(&lh[dst[e0 + i] >> 7], 1u);
        __syncthreads();
        for (int i = t; i < NPART; i += 256) histG[b * NPART + i] = (int)lh[i];
    } else if (b < NB + 128) {
        int o = (b - NB) * 256 + t;                   // 32768 total
        const float* W = (o < 16384) ? W0 : W1;
        f16* T = (o < 16384) ? W0T : W1T;
        int o2 = o & 16383;
        int n = o2 >> 7, k = o2 & 127;
        T[o2] = (f16)W[k * 128 + n];
    } else {
        int o = (b - NB - 128) * 256 + t;             // 4096 total
        int cc = o >> 7, k = o & 127;
        W2T[o] = (cc < CDIM) ? (f16)W2[k * CDIM + cc] : (f16)0.f;
    }
}

// ---------------------------------------------------------------------------
// KH0: h0 = fp16(emb @ W0), 50K x 128. Streaming GEMM: stage 32 fp32 emb
// rows -> fp16 LDS, 4-wave MFMA vs W0T, store h0. No bias/activation
// (bias is added post-aggregation per GCNConv).
// ---------------------------------------------------------------------------
__global__ __launch_bounds__(256, 8) void kh0(const float* __restrict__ emb,
                                              const f16* __restrict__ W0T,
                                              f16* __restrict__ h0) {
    __shared__ f16 Xs[32 * GP];
    int t = threadIdx.x;
    int r0 = blockIdx.x * 32;
    for (int i = t; i < 32 * 32; i += 256) {          // 32 rows x 32 float4
        int row = i >> 5, q = i & 31;
        int v = r0 + row;
        float4 vv = (v < VDIM) ? ((const float4*)emb)[(size_t)v * 32 + q]
                               : make_float4(0.f, 0.f, 0.f, 0.f);
        h4 o; o[0] = (f16)vv.x; o[1] = (f16)vv.y; o[2] = (f16)vv.z; o[3] = (f16)vv.w;
        *(h4*)(Xs + row * GP + q * 4) = o;
    }
    __syncthreads();
    int wave = t >> 6, lane = t & 63;
    int quad = lane >> 4, l15 = lane & 15;
    int mtile = wave & 1, nh = wave >> 1;
    f4 a4[4]; f4 zero = {0.f, 0.f, 0.f, 0.f};
    #pragma unroll
    for (int i = 0; i < 4; ++i) a4[i] = zero;
    #pragma unroll
    for (int kk = 0; kk < 128; kk += 32) {
        h8 a = *(h8*)(Xs + (mtile * 16 + l15) * GP + kk + quad * 8);
        #pragma unroll
        for (int nt4 = 0; nt4 < 4; ++nt4) {
            int nt = nh * 4 + nt4;
            h8 b = *(const h8*)(W0T + (nt * 16 + l15) * 128 + kk + quad * 8);
            a4[nt4] = __builtin_amdgcn_mfma_f32_16x16x32_f16(a, b, a4[nt4], 0, 0, 0);
        }
    }
    #pragma unroll
    for (int nt4 = 0; nt4 < 4; ++nt4) {
        int col = (nh * 4 + nt4) * 16 + l15;
        #pragma unroll
        for (int r = 0; r < 4; ++r) {
            int row = r0 + mtile * 16 + quad * 4 + r;
            if (row < VDIM) h0[(size_t)row * 128 + col] = (f16)a4[nt4][r];
        }
    }
}

// ---------------------------------------------------------------------------
// K2: one wave per partition; scan NB per-block counts (16/lane) -> offsets.
// ---------------------------------------------------------------------------
__global__ __launch_bounds__(256) void k2_seed(int* __restrict__ histG,
                                               int* __restrict__ ptot) {
    int w = blockIdx.x * 4 + (threadIdx.x >> 6);
    if (w >= NPART) return;
    int lane = threadIdx.x & 63;
    int base = w * PCAP;
    int v[16], pre[16], s = 0;
    #pragma unroll
    for (int i = 0; i < 16; ++i) {
        int idx = lane * 16 + i;
        v[i] = (idx < NB) ? histG[idx * NPART + w] : 0;
    }
    #pragma unroll
    for (int i = 0; i < 16; ++i) { pre[i] = s; s += v[i]; }
    int ss = s;
    #pragma unroll
    for (int off = 1; off < 64; off <<= 1) {
        int u = __shfl_up(ss, off);
        if (lane >= off) ss += u;
    }
    if (lane == 63) ptot[w] = ss;                     // partition total
    int wexcl = ss - s;
    #pragma unroll
    for (int i = 0; i < 16; ++i) {
        int idx = lane * 16 + i;
        if (idx < NB) histG[idx * NPART + w] = base + wexcl + pre[i];
    }
}

// ---------------------------------------------------------------------------
// K3: deterministic scatter via LDS cursors seeded from exact offsets.
// ---------------------------------------------------------------------------
__global__ __launch_bounds__(256) void k3_scatter(const int* __restrict__ src,
                                                  const int* __restrict__ dst,
                                                  const float* __restrict__ ew,
                                                  const int* __restrict__ histG,
                                                  uint2* __restrict__ recs) {
    __shared__ unsigned cur[NPART];
    int b = blockIdx.x, t = threadIdx.x;
    for (int i = t; i < NPART; i += 256) cur[i] = (unsigned)histG[b * NPART + i];
    __syncthreads();
    int e0 = b * EPB;
    for (int i = t; i < EPB; i += 256) {
        int e = e0 + i;
        int s = src[e], d = dst[e];
        int p = d >> 7, dl = d & 127;
        unsigned pos = atomicAdd(&cur[p], 1u);        // LDS atomic only
        if (pos < (unsigned)((p + 1) * PCAP)) {       // ~1e-20 overflow guard
            uint2 r; r.x = ((unsigned)dl << 17) | (unsigned)s; r.y = __float_as_uint(ew[e]);
            recs[pos] = r;
        }
    }
}

// ---------------------------------------------------------------------------
// K4: per-partition repack: sort records by dst_local in LDS, emit
// nstart/ncnt, weighted degree -> dinv, strips dl, emits vrec16 = ids[src].
// ---------------------------------------------------------------------------
__global__ __launch_bounds__(256) void k4_repack(uint2* __restrict__ recs,
                                                 const int* __restrict__ ptot,
                                                 const int* __restrict__ ids,
                                                 int* __restrict__ nstart,
                                                 int* __restrict__ ncnt,
                                                 float* __restrict__ dinv,
                                                 unsigned short* __restrict__ vrec16) {
    __shared__ uint2    buf[PBUF];                    // 23.5 KB
    __shared__ float    wsum[128];
    __shared__ unsigned hcnt[128], pref[128], cur[128];
    int p = blockIdx.x, t = threadIdx.x;
    if (t < 128) { hcnt[t] = 0; wsum[t] = 0.f; }
    __syncthreads();
    int base = p * PCAP;
    int c = ptot[p];
    if (c > PCAP) c = PCAP;
    for (int i = t; i < c; i += 256) {
        uint2 r = recs[base + i];
        buf[i] = r;
        int dl = r.x >> 17;
        atomicAdd(&hcnt[dl], 1u);
        atomicAdd(&wsum[dl], __uint_as_float(r.y));
    }
    __syncthreads();
    if (t == 0) {
        unsigned s = 0;
        for (int k = 0; k < 128; ++k) { pref[k] = s; s += hcnt[k]; }
    }
    __syncthreads();
    if (t < 128) {
        cur[t] = pref[t];
        int g = p * 128 + t;
        if (g < N_NODES) {
            nstart[g] = base + (int)pref[t];
            ncnt[g]   = (int)hcnt[t];
            dinv[g]   = rsqrtf(wsum[t] + 1.0f);
        }
    }
    __syncthreads();
    for (int i = t; i < c; i += 256) {
        uint2 r = buf[i];
        int dl = r.x >> 17;
        unsigned pos = atomicAdd(&cur[dl], 1u);
        int s = (int)(r.x & 0x1FFFFu);
        uint2 o; o.x = (unsigned)s; o.y = r.y;
        recs[base + pos]   = o;
        vrec16[base + pos] = (unsigned short)ids[s];
    }
}

// ---------------------------------------------------------------------------
// fusedL0g: layer 0 as PURE aggregation of h0 rows (no MFMA, no LDS).
// x1[n] = leaky( dn*sum cf*h0[vid(src)] + dn^2*h0[ids[n]] + b0 ).
// R15/R20-proven interleaved wave structure: lane owns 2 features of 8
// nodes; (vid, cf) prefetched (32 recs/node, half-wave packed), readlane
// broadcast; cf pre-zeroed beyond degree. Gather table is 12.8MB (vs 25.6).
// ---------------------------------------------------------------------------
__global__ __launch_bounds__(256, 8) void fusedL0g(const f16* __restrict__ h0,
                                                   const int* __restrict__ ids,
                                                   const float* __restrict__ dinv,
                                                   const int* __restrict__ nstart,
                                                   const int* __restrict__ ncnt,
                                                   const uint2* __restrict__ recs,
                                                   const unsigned short* __restrict__ vrec16,
                                                   const float* __restrict__ b0,
                                                   f16* __restrict__ Xo) {
    int t = threadIdx.x;
    int wave = t >> 6, lane = t & 63;
    int nb = blockIdx.x * 32 + wave * 8;
    int half = lane >> 5, li = lane & 31;

    int   si[4];
    float cf[4];
    #pragma unroll
    for (int r = 0; r < 4; ++r) {
        int node = nb + 2 * r + half;
        int st = nstart[node], c = ncnt[node];
        int ci = li < c ? li : (c > 0 ? c - 1 : 0);
        int addr = st + ci;
        if (addr >= RTOT) addr = RTOT - 1;
        uint2 r0 = recs[addr];
        int s = (int)(r0.x & 0x1FFFFu);               // src (dinv OOB-safe in ws)
        unsigned v = vrec16[addr];
        if (v >= VDIM) v = 0;                         // garbage-slot clamp
        si[r] = (int)v;
        cf[r] = (li < c) ? dinv[s] * __uint_as_float(r0.y) : 0.f;
    }

    int maxc = 0, maxcall = 0;
    #pragma unroll
    for (int nn = 0; nn < 8; ++nn) {
        int c = ncnt[nb + nn];
        maxcall = c > maxcall ? c : maxcall;
        int cc = c < 32 ? c : 32;
        maxc = cc > maxc ? cc : maxc;
    }

    float acc[16];
    #pragma unroll
    for (int k = 0; k < 16; ++k) acc[k] = 0.f;

    const f16* xcol = h0 + lane * 2;                  // lane's 2-feature column
    #pragma unroll 4
    for (int j = 0; j < maxc; ++j) {
        #pragma unroll
        for (int r = 0; r < 4; ++r) {
            int   s0 = __builtin_amdgcn_readlane(si[r], j);
            int   s1 = __builtin_amdgcn_readlane(si[r], j + 32);
            float w0 = __uint_as_float(__builtin_amdgcn_readlane(__float_as_uint(cf[r]), j));
            float w1 = __uint_as_float(__builtin_amdgcn_readlane(__float_as_uint(cf[r]), j + 32));
            h2 v0 = *(const h2*)(xcol + (size_t)s0 * 128);
            h2 v1 = *(const h2*)(xcol + (size_t)s1 * 128);
            acc[4 * r + 0] += w0 * (float)v0[0];
            acc[4 * r + 1] += w0 * (float)v0[1];
            acc[4 * r + 2] += w1 * (float)v1[0];
            acc[4 * r + 3] += w1 * (float)v1[1];
        }
    }

    if (maxcall > 32) {                               // rare tail (deg > 32)
        for (int nn = 0; nn < 8; ++nn) {
            int node = nb + nn;
            int st = nstart[node], c = ncnt[node];
            for (int j = 32; j < c; ++j) {
                uint2 rr = recs[st + j];
                int s = (int)(rr.x & 0x1FFFFu);
                float w = dinv[s] * __uint_as_float(rr.y);
                int vv = ids[s];
                h2 v = *(const h2*)(xcol + (size_t)vv * 128);
                acc[2 * nn]     += w * (float)v[0];
                acc[2 * nn + 1] += w * (float)v[1];
            }
        }
    }

    float bb0 = b0[lane * 2], bb1 = b0[lane * 2 + 1];
    #pragma unroll
    for (int nn = 0; nn < 8; ++nn) {
        int node = nb + nn;
        float dn = dinv[node], d2 = dn * dn;
        int vn = ids[node];
        h2 sv = *(const h2*)(xcol + (size_t)vn * 128);
        float v0 = dn * acc[2 * nn]     + d2 * (float)sv[0] + bb0;
        float v1 = dn * acc[2 * nn + 1] + d2 * (float)sv[1] + bb1;
        v0 = v0 > 0.f ? v0 : NEG_SLOPE * v0;
        v1 = v1 > 0.f ? v1 : NEG_SLOPE * v1;
        h2 o; o[0] = (f16)v0; o[1] = (f16)v1;
        *(h2*)(Xo + (size_t)node * 128 + lane * 2) = o;
    }
}

// ---------------------------------------------------------------------------
// agg helper for L1 (R20-proven verbatim): rec=(src,ew), dinv folded in
// prefetch, readlane broadcast, z-tile to LDS for the MFMA.
// ---------------------------------------------------------------------------
__device__ __forceinline__ void agg_to_lds(const f16* __restrict__ Xi,
                                           const float* __restrict__ dinv,
                                           const int* __restrict__ nstart,
                                           const int* __restrict__ ncnt,
                                           const uint2* __restrict__ recs,
                                           f16* __restrict__ Xs,
                                           int wave, int lane, int nb) {
    int half = lane >> 5;
    int li   = lane & 31;

    int   si[4];
    float cf[4];
    #pragma unroll
    for (int r = 0; r < 4; ++r) {
        int node = nb + 2 * r + half;
        int st = nstart[node], c = ncnt[node];
        int ci = li < c ? li : (c > 0 ? c - 1 : 0);
        int addr = st + ci;
        if (addr >= RTOT) addr = RTOT - 1;
        uint2 r0 = recs[addr];
        int s = (int)(r0.x & 0x1FFFFu);
        si[r] = s;
        cf[r] = (li < c) ? dinv[s] * __uint_as_float(r0.y) : 0.f;
    }

    int maxc = 0, maxcall = 0;
    #pragma unroll
    for (int nn = 0; nn < 8; ++nn) {
        int c = ncnt[nb + nn];
        maxcall = c > maxcall ? c : maxcall;
        int cc = c < 32 ? c : 32;
        maxc = cc > maxc ? cc : maxc;
    }

    float acc[16];
    #pragma unroll
    for (int k = 0; k < 16; ++k) acc[k] = 0.f;

    const f16* xcol = Xi + lane * 2;
    #pragma unroll 4
    for (int j = 0; j < maxc; ++j) {
        #pragma unroll
        for (int r = 0; r < 4; ++r) {
            int   s0 = __builtin_amdgcn_readlane(si[r], j);
            int   s1 = __builtin_amdgcn_readlane(si[r], j + 32);
            float w0 = __uint_as_float(__builtin_amdgcn_readlane(__float_as_uint(cf[r]), j));
            float w1 = __uint_as_float(__builtin_amdgcn_readlane(__float_as_uint(cf[r]), j + 32));
            h2 v0 = *(const h2*)(xcol + (size_t)s0 * 128);
            h2 v1 = *(const h2*)(xcol + (size_t)s1 * 128);
            acc[4 * r + 0] += w0 * (float)v0[0];
            acc[4 * r + 1] += w0 * (float)v0[1];
            acc[4 * r + 2] += w1 * (float)v1[0];
            acc[4 * r + 3] += w1 * (float)v1[1];
        }
    }

    if (maxcall > 32) {
        for (int nn = 0; nn < 8; ++nn) {
            int node = nb + nn;
            int st = nstart[node], c = ncnt[node];
            for (int j = 32; j < c; ++j) {
                uint2 rr = recs[st + j];
                int s = (int)(rr.x & 0x1FFFFu);
                float w = dinv[s] * __uint_as_float(rr.y);
                h2 v = *(const h2*)(xcol + (size_t)s * 128);
                acc[2 * nn]     += w * (float)v[0];
                acc[2 * nn + 1] += w * (float)v[1];
            }
        }
    }

    #pragma unroll
    for (int nn = 0; nn < 8; ++nn) {
        int node = nb + nn;
        float dn = dinv[node], d2 = dn * dn;
        h2 sv = *(const h2*)(xcol + (size_t)node * 128);
        h2 o;
        o[0] = (f16)(dn * acc[2 * nn]     + d2 * (float)sv[0]);
        o[1] = (f16)(dn * acc[2 * nn + 1] + d2 * (float)sv[1]);
        *(h2*)(Xs + (wave * 8 + nn) * GP + lane * 2) = o;
    }
}

// ---------------------------------------------------------------------------
// fusedL1: agg + 128x128 MFMA + leaky -> LDS + 128->20 GEMM (R20 verbatim).
// ---------------------------------------------------------------------------
__global__ __launch_bounds__(256, 8) void fusedL1(const f16* __restrict__ Xi,
                                                  const float* __restrict__ dinv,
                                                  const int* __restrict__ nstart,
                                                  const int* __restrict__ ncnt,
                                                  const uint2* __restrict__ recs,
                                                  const f16* __restrict__ WT,
                                                  const float* __restrict__ bias,
                                                  const f16* __restrict__ W2T,
                                                  f16* __restrict__ Y) {
    __shared__ f16 Xs[32 * GP];
    int t = threadIdx.x;
    int wave = t >> 6, lane = t & 63;
    agg_to_lds(Xi, dinv, nstart, ncnt, recs, Xs, wave, lane,
               blockIdx.x * 32 + wave * 8);
    __syncthreads();

    int quad = lane >> 4, l15 = lane & 15;
    int mtile = wave & 1, nh = wave >> 1;
    f4 a4[4]; f4 zero = {0.f, 0.f, 0.f, 0.f};
    #pragma unroll
    for (int i = 0; i < 4; ++i) a4[i] = zero;
    #pragma unroll
    for (int kk = 0; kk < 128; kk += 32) {
        h8 a = *(h8*)(Xs + (mtile * 16 + l15) * GP + kk + quad * 8);
        #pragma unroll
        for (int nt4 = 0; nt4 < 4; ++nt4) {
            int nt = nh * 4 + nt4;
            h8 b = *(const h8*)(WT + (nt * 16 + l15) * 128 + kk + quad * 8);
            a4[nt4] = __builtin_amdgcn_mfma_f32_16x16x32_f16(a, b, a4[nt4], 0, 0, 0);
        }
    }
    __syncthreads();                                  // z reads done
    #pragma unroll
    for (int nt4 = 0; nt4 < 4; ++nt4) {               // x2 = leaky(acc+b) -> LDS
        int col = (nh * 4 + nt4) * 16 + l15;
        float bb = bias[col];
        #pragma unroll
        for (int r = 0; r < 4; ++r) {
            float v = a4[nt4][r] + bb;
            v = v > 0.f ? v : NEG_SLOPE * v;
            Xs[(mtile * 16 + quad * 4 + r) * GP + col] = (f16)v;
        }
    }
    __syncthreads();
    int mt2 = wave & 1, nt2 = wave >> 1;              // 32x32 y tile, 4 waves
    f4 ya = zero;
    #pragma unroll
    for (int kk = 0; kk < 128; kk += 32) {
        h8 a = *(h8*)(Xs + (mt2 * 16 + l15) * GP + kk + quad * 8);
        h8 b = *(const h8*)(W2T + (nt2 * 16 + l15) * 128 + kk + quad * 8);
        ya = __builtin_amdgcn_mfma_f32_16x16x32_f16(a, b, ya, 0, 0, 0);
    }
    size_t rbase = (size_t)blockIdx.x * 32;
    #pragma unroll
    for (int r = 0; r < 4; ++r) {
        size_t row = rbase + mt2 * 16 + quad * 4 + r;
        Y[row * 32 + nt2 * 16 + l15] = (f16)ya[r];
    }
}

// ---------------------------------------------------------------------------
// agg20L: out = LSM( b2 + dn*sum(dinv[s]*ew*Y[s]) + dn^2*Y[n] ).
// ---------------------------------------------------------------------------
__global__ __launch_bounds__(256) void agg20L(const f16* __restrict__ Y,
                                              const float* __restrict__ dinv,
                                              const int* __restrict__ nstart,
                                              const int* __restrict__ ncnt,
                                              const uint2* __restrict__ recs,
                                              const float* __restrict__ b2,
                                              float* __restrict__ out) {
    int wave = threadIdx.x >> 6, lane = threadIdx.x & 63;
    int g = lane >> 3, l7 = lane & 7;
    int node = blockIdx.x * 4 + wave;
    int st = nstart[node], c = ncnt[node];

    int ci = lane < c ? lane : (c > 0 ? c - 1 : 0);
    int addr = st + ci;
    if (addr >= RTOT) addr = RTOT - 1;
    uint2 r0 = recs[addr];
    int   sidx0 = (int)(r0.x & 0x1FFFFu);
    float cf0 = (lane < c) ? dinv[sidx0] * __uint_as_float(r0.y) : 0.f;

    float acc[4];
    #pragma unroll
    for (int k = 0; k < 4; ++k) acc[k] = 0.f;

    int cl = c < 64 ? c : 64;
    #pragma unroll 4
    for (int j = 0; j < cl; j += 8) {
        int jj = j + g;
        float cc = __shfl(cf0, jj);
        int   si = __shfl(sidx0, jj);
        h4 hh = *(const h4*)(Y + (size_t)si * 32 + l7 * 4);
        #pragma unroll
        for (int k = 0; k < 4; ++k) acc[k] += cc * (float)hh[k];
    }
    for (int j = 64; j < c; j += 8) {                 // rare spill-over
        int jj = j + g;
        int idx = st + (jj < c ? jj : c - 1);
        uint2 r = recs[idx];
        int s = (int)(r.x & 0x1FFFFu);
        float cf = dinv[s] * __uint_as_float(r.y);
        float cc = (jj < c) ? cf : 0.f;
        h4 hh = *(const h4*)(Y + (size_t)s * 32 + l7 * 4);
        #pragma unroll
        for (int k = 0; k < 4; ++k) acc[k] += cc * (float)hh[k];
    }
    #pragma unroll
    for (int k = 0; k < 4; ++k) {
        acc[k] += __shfl_xor(acc[k], 8);
        acc[k] += __shfl_xor(acc[k], 16);
        acc[k] += __shfl_xor(acc[k], 32);
    }
    float dn = dinv[node], d2 = dn * dn;
    h4 hz = *(const h4*)(Y + (size_t)node * 32 + l7 * 4);
    bool live = (l7 < 5);                             // 5 lanes x 4 = 20 classes
    float tv[4];
    float mx = -INFINITY;
    #pragma unroll
    for (int k = 0; k < 4; ++k) {
        tv[k] = live ? (b2[l7 * 4 + k] + dn * acc[k] + d2 * (float)hz[k]) : -INFINITY;
        mx = fmaxf(mx, tv[k]);
    }
    #pragma unroll
    for (int off = 1; off <= 4; off <<= 1) mx = fmaxf(mx, __shfl_xor(mx, off));
    float ex = 0.f;
    if (live) {
        #pragma unroll
        for (int k = 0; k < 4; ++k) ex += expf(tv[k] - mx);
    }
    #pragma unroll
    for (int off = 1; off <= 4; off <<= 1) ex += __shfl_xor(ex, off);
    float ls = logf(ex);
    if (g == 0 && live) {
        float4 o;
        o.x = tv[0] - mx - ls; o.y = tv[1] - mx - ls;
        o.z = tv[2] - mx - ls; o.w = tv[3] - mx - ls;
        *(float4*)(out + (size_t)node * CDIM + l7 * 4) = o;
    }
}

// ---------------------------------------------------------------------------
extern "C" void kernel_launch(void* const* d_in, const int* in_sizes, int n_in,
                              void* d_out, int out_size, void* d_ws, size_t ws_size,
                              hipStream_t stream) {
    (void)in_sizes; (void)n_in; (void)out_size; (void)ws_size;
    const int*   node_ids = (const int*)d_in[0];
    const int*   e_src    = (const int*)d_in[1];
    const int*   e_dst    = e_src + N_EDGES;
    const float* edge_w   = (const float*)d_in[2];
    const float* emb      = (const float*)d_in[3];
    const float* W0       = (const float*)d_in[4];
    const float* b0       = (const float*)d_in[5];
    const float* W1       = (const float*)d_in[6];
    const float* b1       = (const float*)d_in[7];
    const float* W2       = (const float*)d_in[8];
    const float* b2       = (const float*)d_in[9];
    float* out = (float*)d_out;

    char* w = (char*)d_ws;
    size_t off = 0;
    auto alloc = [&](size_t bytes) {
        void* p = w + off;
        off = (off + bytes + 255) & ~(size_t)255;
        return p;
    };
    f16*   h0     = (f16*)alloc((size_t)VDIM * FDIM * 2);        // 12.8 MB
    f16*   xB     = (f16*)alloc((size_t)N_NODES * FDIM * 2);     // 25.6 MB (also OOB pad for h0)
    f16*   ybuf   = (f16*)alloc((size_t)N_NODES * 32 * 2);       // 6.4 MB
    int*   histG  = (int*)alloc((size_t)NB * NPART * 4);         // 3.1 MB
    int*   ptot   = (int*)alloc((size_t)NPART * 4);
    int*   nstart = (int*)alloc((size_t)N_NODES * 4);
    int*   ncnt   = (int*)alloc((size_t)N_NODES * 4);
    float* dinv   = (float*)alloc((size_t)N_NODES * 4 + 131072 * 4);  // +OOB pad
    f16*   W0T    = (f16*)alloc(16384 * 2);
    f16*   W1T    = (f16*)alloc(16384 * 2);
    f16*   W2T    = (f16*)alloc(32 * 128 * 2);
    uint2* recs   = (uint2*)alloc((size_t)NPART * PCAP * 8);     // 16.0 MB
    unsigned short* vrec16 = (unsigned short*)alloc((size_t)NPART * PCAP * 2); // 4 MB

    k1_build<<<NB + 128 + 16, 256, 0, stream>>>(
        e_dst, histG, W0, W1, W2, W0T, W1T, W2T);
    k2_seed<<<(NPART + 3) / 4, 256, 0, stream>>>(histG, ptot);
    kh0<<<(VDIM + 31) / 32, 256, 0, stream>>>(emb, W0T, h0);     // h0 = emb @ W0
    k3_scatter<<<NB, 256, 0, stream>>>(e_src, e_dst, edge_w, histG, recs);
    k4_repack<<<NPART, 256, 0, stream>>>(recs, ptot, node_ids, nstart, ncnt, dinv, vrec16);

    int fblocks = N_NODES / 32;                      // 3125 exact
    // layer 0:  x1 = leaky(A.(emb@W0) + b0) — pure gather-agg over h0 (12.8MB table)
    fusedL0g<<<fblocks, 256, 0, stream>>>(h0, node_ids, dinv, nstart, ncnt,
                                          recs, vrec16, b0, xB);
    // layer 1 + 128->20:  y = leaky((A.x1) W1 + b1) W2   (x2 never hits HBM)
    fusedL1<<<fblocks, 256, 0, stream>>>(xB, dinv, nstart, ncnt, recs, W1T, b1, W2T, ybuf);
    // out = LSM(b2 + A.y)
    agg20L<<<N_NODES / 4, 256, 0, stream>>>(ybuf, dinv, nstart, ncnt, recs, b2, out);
}